// Round 1
// baseline (1031.226 us; speedup 1.0000x reference)
//
#include <hip/hip_runtime.h>
#include <cstdint>
#include <cstddef>

// Problem constants
#define NWIN 2048
#define NW   144          // 12*12 tokens per window
#define DIM  256
#define NHD  8
#define HD   32
#define MTOT (NWIN * NW)  // 294912 rows
#define SCALE 0.17677669529663687f  // HD^-0.5

typedef __bf16 bf16x8 __attribute__((ext_vector_type(8)));
typedef float  f32x4  __attribute__((ext_vector_type(4)));
typedef unsigned short u16;
typedef unsigned short u16x4 __attribute__((ext_vector_type(4)));

__device__ __forceinline__ u16 f2bf(float f) {
  unsigned u = __float_as_uint(f);
  u += 0x7fffu + ((u >> 16) & 1u);   // round-to-nearest-even
  return (u16)(u >> 16);
}

__device__ __forceinline__ bf16x8 pack8(f32x4 lo, f32x4 hi) {
  union { bf16x8 v; u16 u[8]; } o;
  o.u[0] = f2bf(lo.x); o.u[1] = f2bf(lo.y); o.u[2] = f2bf(lo.z); o.u[3] = f2bf(lo.w);
  o.u[4] = f2bf(hi.x); o.u[5] = f2bf(hi.y); o.u[6] = f2bf(hi.z); o.u[7] = f2bf(hi.w);
  return o.v;
}

__device__ __forceinline__ f32x4 mfma16(bf16x8 a, bf16x8 b, f32x4 c) {
  return __builtin_amdgcn_mfma_f32_16x16x32_bf16(a, b, c, 0, 0, 0);
}

// ---------------- P2: weights -> B^T bf16; bias gather ----------------
__global__ void k_prep(const float* __restrict__ qkv_w, const float* __restrict__ proj_w,
                       const float* __restrict__ rpb, const int* __restrict__ rel,
                       u16* __restrict__ wqkvt, u16* __restrict__ wprojt,
                       float* __restrict__ biasar) {
  int tid = blockIdx.x * blockDim.x + threadIdx.x;
  int stride = gridDim.x * blockDim.x;
  // wqkvt[n][k] = bf16(qkv_w[k][n]),  n<768, k<256
  for (int i = tid; i < 768 * 256; i += stride) {
    int n = i >> 8, k = i & 255;
    wqkvt[i] = f2bf(qkv_w[(size_t)k * 768 + n]);
  }
  // wprojt[n][k] = bf16(proj_w[k][n]), n<256, k<256
  for (int i = tid; i < 256 * 256; i += stride) {
    int n = i >> 8, k = i & 255;
    wprojt[i] = f2bf(proj_w[(size_t)k * 256 + n]);
  }
  // biasar[h][n][m] = rpb[rel[n*144+m]][h]  (fp32, dense)
  for (int i = tid; i < NW * NW; i += stride) {
    int idv = rel[i];
#pragma unroll
    for (int hh = 0; hh < 8; ++hh) biasar[hh * (NW * NW) + i] = rpb[idv * 8 + hh];
  }
}

// ---------------- GEMM: out[M][N] = A[M][256] * Bt[N][256]^T + bias ----------------
// 128x128 tile, BK=64, 4 waves (2x2), 16x16x32 bf16 MFMA.
// LDS chunks XOR-swizzled (chunk c stored at c^(row&7)) -> frag reads are 2-way (free).
// AF32: A is fp32, converted to bf16 during staging (fuses the old k_cvt_x pass).
template <int NT, bool AF32, bool OUTF32>
__global__ __launch_bounds__(256) void k_gemm_bt(const void* __restrict__ Av,
                                                 const u16* __restrict__ Bt,
                                                 const float* __restrict__ bias,
                                                 void* __restrict__ outv) {
  constexpr int N = NT * 128;
  __shared__ __align__(16) u16 As[128 * 64];
  __shared__ __align__(16) u16 Bs[128 * 64];
  int tid = threadIdx.x;
  int wave = tid >> 6, lane = tid & 63;
  int ln = lane & 15, quad = lane >> 4;
  int wm = wave >> 1, wn = wave & 1;

  // XCD swizzle: all NT column-tiles of one M-tile on the same XCD (A-tile L2 reuse).
  int bid = blockIdx.x;
  int xcd = bid & 7, slot = bid >> 3;
  int mt = xcd * 288 + slot / NT;  // 2304 M-tiles / 8 XCDs = 288
  int nt = slot % NT;
  int m0 = mt * 128, n0 = nt * 128;

  f32x4 zero4 = {0.f, 0.f, 0.f, 0.f};
  f32x4 acc[4][4];
#pragma unroll
  for (int i = 0; i < 4; ++i)
#pragma unroll
    for (int j = 0; j < 4; ++j) acc[i][j] = zero4;

  for (int kt = 0; kt < 4; ++kt) {
    int k0 = kt * 64;
    bf16x8 avs[4], bvs[4];
#pragma unroll
    for (int i = 0; i < 4; ++i) {
      int s = i * 256 + tid;       // 0..1023 chunk id
      int r = s >> 3, c = s & 7;   // row 0..127, 16B-chunk 0..7
      if constexpr (AF32) {
        const float* Af = (const float*)Av;
        const float* p = &Af[(size_t)(m0 + r) * 256 + k0 + c * 8];
        f32x4 lo = *(const f32x4*)p;
        f32x4 hi = *(const f32x4*)(p + 4);
        avs[i] = pack8(lo, hi);
      } else {
        const u16* Ab = (const u16*)Av;
        avs[i] = *(const bf16x8*)&Ab[(size_t)(m0 + r) * 256 + k0 + c * 8];
      }
      bvs[i] = *(const bf16x8*)&Bt[(size_t)(n0 + r) * 256 + k0 + c * 8];
    }
    if (kt) __syncthreads();  // previous tile's reads done before overwrite
#pragma unroll
    for (int i = 0; i < 4; ++i) {
      int s = i * 256 + tid;
      int r = s >> 3, c = s & 7;
      int dst = r * 64 + (((c ^ (r & 7))) << 3);
      *(bf16x8*)&As[dst] = avs[i];
      *(bf16x8*)&Bs[dst] = bvs[i];
    }
    __syncthreads();
#pragma unroll
    for (int ks = 0; ks < 2; ++ks) {
      bf16x8 af[4], bfr[4];
#pragma unroll
      for (int t = 0; t < 4; ++t) {
        int rowa = wm * 64 + t * 16 + ln;
        int rowb = wn * 64 + t * 16 + ln;
        int ca = ks * 4 + quad;
        af[t]  = *(const bf16x8*)&As[rowa * 64 + ((ca ^ (rowa & 7)) << 3)];
        bfr[t] = *(const bf16x8*)&Bs[rowb * 64 + ((ca ^ (rowb & 7)) << 3)];
      }
#pragma unroll
      for (int i = 0; i < 4; ++i)
#pragma unroll
        for (int j = 0; j < 4; ++j) acc[i][j] = mfma16(af[i], bfr[j], acc[i][j]);
    }
  }

  // Epilogue: C/D layout col=lane&15, row=quad*4+reg (m89-verified).
#pragma unroll
  for (int j = 0; j < 4; ++j) {
    int col = n0 + wn * 64 + j * 16 + ln;
    float bv = bias[col];
#pragma unroll
    for (int i = 0; i < 4; ++i) {
      int rbase = m0 + wm * 64 + i * 16 + quad * 4;
      f32x4 a = acc[i][j];
      if constexpr (OUTF32) {
        float* out = (float*)outv;
#pragma unroll
        for (int r = 0; r < 4; ++r) out[(size_t)(rbase + r) * N + col] = a[r] + bv;
      } else {
        u16* out = (u16*)outv;
#pragma unroll
        for (int r = 0; r < 4; ++r) out[(size_t)(rbase + r) * N + col] = f2bf(a[r] + bv);
      }
    }
  }
}

// ---------------- K2: per-(window,head) attention ----------------
// 3 waves; wave owns 48 query rows (3 row-tiles). S = qk^T via one MFMA per frag
// (K=32=HD). Softmax in C-layout regs (shuffle over the 16-lane col group);
// P converted to packed bf16 REGISTERS during softmax (halves P-state, frees accs).
// P -> A-layout via chunked LDS round-trip; Sp ALIASES Sq/Sk (dead by then):
// LDS 54KB -> 33.3KB => 4 blocks/CU (12 waves/CU) instead of 2.
__global__ __launch_bounds__(192, 3) void k_attn(const u16* __restrict__ qkv,
                                                 const float* __restrict__ bias_arr,
                                                 u16* __restrict__ attn_out) {
  // Union region: [Sq 144*40 | Sk 144*40] = 23040B, reused as Sp 144*72 = 20736B.
  __shared__ __align__(16) u16 SqSk[144 * 40 * 2];
  __shared__ __align__(16) u16 Sv[32 * 160];   // v^T [d][m], m padded 144..159 = 0
  u16* Sq = SqSk;
  u16* Sk = SqSk + 144 * 40;
  u16* Sp = SqSk;                              // alias: live only after Sq/Sk dead

  int bid = blockIdx.x;
  int xcd = bid & 7, idx = bid >> 3;
  int w = xcd * 256 + (idx >> 3);  // all 8 heads of a window on one XCD (line sharing)
  int h = idx & 7;

  int tid = threadIdx.x;
  const u16* base = qkv + (size_t)w * (NW * 768);
  int qo = h * 32, ko = 256 + h * 32, vo = 512 + h * 32;

#pragma unroll
  for (int it = 0; it < 3; ++it) {
    int s = tid + it * 192;          // 576 = 144 rows * 4 chunks
    int r = s >> 2, c = (s & 3) << 3;
    *(bf16x8*)&Sq[r * 40 + c] = *(const bf16x8*)&base[(size_t)r * 768 + qo + c];
    *(bf16x8*)&Sk[r * 40 + c] = *(const bf16x8*)&base[(size_t)r * 768 + ko + c];
    bf16x8 vv = *(const bf16x8*)&base[(size_t)r * 768 + vo + c];
#pragma unroll
    for (int j = 0; j < 8; ++j) Sv[(c + j) * 160 + r] = ((u16*)&vv)[j];  // transpose
  }
  for (int s = tid; s < 32 * 16; s += 192) {   // zero-pad v^T cols 144..159
    int d = s >> 4, m = 144 + (s & 15);
    Sv[d * 160 + m] = 0;
  }
  __syncthreads();

  int wv = tid >> 6;
  int lane = tid & 63, ln = lane & 15, quad = lane >> 4;

  f32x4 zero4 = {0.f, 0.f, 0.f, 0.f};
  f32x4 accs[3][9];
#pragma unroll
  for (int i = 0; i < 3; ++i)
#pragma unroll
    for (int j = 0; j < 9; ++j) accs[i][j] = zero4;

  bf16x8 aq[3];
#pragma unroll
  for (int mt = 0; mt < 3; ++mt) {
    int row = (wv * 3 + mt) * 16 + ln;
    aq[mt] = *(const bf16x8*)&Sq[row * 40 + quad * 8];
  }
#pragma unroll
  for (int j = 0; j < 9; ++j) {
    bf16x8 bk = *(const bf16x8*)&Sk[(j * 16 + ln) * 40 + quad * 8];
#pragma unroll
    for (int mt = 0; mt < 3; ++mt) accs[mt][j] = mfma16(aq[mt], bk, accs[mt][j]);
  }

  // softmax (rows wave-local; cols live on the 16-lane group + 9 frags in-lane)
  // P packed to bf16 regs: pb[mt][j][r] = bf16(P[n=..+quad*4+r][m=j*16+ln])
  u16x4 pb[3][9];
  const float* bh = bias_arr + h * (NW * NW);
#pragma unroll
  for (int mt = 0; mt < 3; ++mt) {
#pragma unroll
    for (int r = 0; r < 4; ++r) {
      int n = (wv * 3 + mt) * 16 + quad * 4 + r;
      float sv[9];
      float mx = -3.0e38f;
#pragma unroll
      for (int j = 0; j < 9; ++j) {
        sv[j] = accs[mt][j][r] * SCALE + bh[n * 144 + j * 16 + ln];
        mx = fmaxf(mx, sv[j]);
      }
#pragma unroll
      for (int off = 1; off < 16; off <<= 1) mx = fmaxf(mx, __shfl_xor(mx, off));
      float sum = 0.f;
#pragma unroll
      for (int j = 0; j < 9; ++j) { sv[j] = __expf(sv[j] - mx); sum += sv[j]; }
#pragma unroll
      for (int off = 1; off < 16; off <<= 1) sum += __shfl_xor(sum, off);
      float inv = 1.f / sum;
#pragma unroll
      for (int j = 0; j < 9; ++j) pb[mt][j][r] = f2bf(sv[j] * inv);
    }
  }
  // accs dead from here on.

  // PV in 3 column chunks of 64 (last chunk: 16 real cols + 16 zero, 1 K-step)
  f32x4 acco[3][2];
#pragma unroll
  for (int i = 0; i < 3; ++i) { acco[i][0] = zero4; acco[i][1] = zero4; }

#pragma unroll
  for (int cc = 0; cc < 3; ++cc) {
    __syncthreads();  // previous chunk's (or Sq/Sk's) reads complete before overwrite
    int njj = (cc == 2) ? 2 : 4;
#pragma unroll
    for (int mt = 0; mt < 3; ++mt)
#pragma unroll
      for (int r = 0; r < 4; ++r) {
        int n = (wv * 3 + mt) * 16 + quad * 4 + r;
#pragma unroll
        for (int jj = 0; jj < 4; ++jj) {
          if (jj >= njj) break;
          int jg = cc * 4 + jj;
          u16 val;
          if (jg < 9) val = pb[mt][jg][r]; else val = (u16)0;
          Sp[n * 72 + jj * 16 + ln] = val;
        }
      }
    __syncthreads();
    int nks = (cc == 2) ? 1 : 2;
#pragma unroll
    for (int ks = 0; ks < 2; ++ks) {
      if (ks >= nks) break;
      int kg = cc * 64 + ks * 32;
      bf16x8 bv0 = *(const bf16x8*)&Sv[ln * 160 + kg + quad * 8];
      bf16x8 bv1 = *(const bf16x8*)&Sv[(16 + ln) * 160 + kg + quad * 8];
#pragma unroll
      for (int mt = 0; mt < 3; ++mt) {
        int row = (wv * 3 + mt) * 16 + ln;
        bf16x8 ap = *(const bf16x8*)&Sp[row * 72 + ks * 32 + quad * 8];
        acco[mt][0] = mfma16(ap, bv0, acco[mt][0]);
        acco[mt][1] = mfma16(ap, bv1, acco[mt][1]);
      }
    }
  }

  u16* op = attn_out + (size_t)w * (NW * 256) + h * 32;
#pragma unroll
  for (int mt = 0; mt < 3; ++mt)
#pragma unroll
    for (int d2 = 0; d2 < 2; ++d2) {
      f32x4 a = acco[mt][d2];
      int col = d2 * 16 + ln;
#pragma unroll
      for (int r = 0; r < 4; ++r) {
        int n = (wv * 3 + mt) * 16 + quad * 4 + r;
        op[(size_t)n * 256 + col] = f2bf(a[r]);
      }
    }
}

// ---------------- launcher ----------------
extern "C" void kernel_launch(void* const* d_in, const int* in_sizes, int n_in,
                              void* d_out, int out_size, void* d_ws, size_t ws_size,
                              hipStream_t stream) {
  const float* x      = (const float*)d_in[0];
  const float* qkv_w  = (const float*)d_in[1];
  const float* qkv_b  = (const float*)d_in[2];
  const float* proj_w = (const float*)d_in[3];
  const float* proj_b = (const float*)d_in[4];
  const float* rpb    = (const float*)d_in[5];
  const int*   rel    = (const int*)d_in[6];
  float* out = (float*)d_out;

  // ws layout (~605 MiB total): qkv bf16 | attn_out bf16 | W^T bf16 | bias f32
  u16* qkv    = (u16*)d_ws;
  u16* attno  = qkv + (size_t)MTOT * 768;
  u16* wqkvt  = attno + (size_t)MTOT * 256;
  u16* wprojt = wqkvt + 768 * 256;
  float* biasar = (float*)(wprojt + 256 * 256);

  k_prep<<<256, 256, 0, stream>>>(qkv_w, proj_w, rpb, rel, wqkvt, wprojt, biasar);
  k_gemm_bt<6, true,  false><<<13824, 256, 0, stream>>>(x, wqkvt, qkv_b, (void*)qkv);
  k_attn<<<16384, 192, 0, stream>>>(qkv, biasar, attno);
  k_gemm_bt<2, false, true><<<4608, 256, 0, stream>>>(attno, wprojt, proj_b, (void*)out);
}

// Round 2
// 1028.189 us; speedup vs baseline: 1.0030x; 1.0030x over previous
//
#include <hip/hip_runtime.h>
#include <cstdint>
#include <cstddef>

// Problem constants
#define NWIN 2048
#define NW   144          // 12*12 tokens per window
#define DIM  256
#define NHD  8
#define HD   32
#define MTOT (NWIN * NW)  // 294912 rows
#define SCALE 0.17677669529663687f  // HD^-0.5

typedef __bf16 bf16x8 __attribute__((ext_vector_type(8)));
typedef float  f32x4  __attribute__((ext_vector_type(4)));
typedef unsigned short u16;
typedef unsigned short u16x4 __attribute__((ext_vector_type(4)));

__device__ __forceinline__ u16 f2bf(float f) {
  unsigned u = __float_as_uint(f);
  u += 0x7fffu + ((u >> 16) & 1u);   // round-to-nearest-even
  return (u16)(u >> 16);
}

__device__ __forceinline__ bf16x8 pack8(f32x4 lo, f32x4 hi) {
  union { bf16x8 v; u16 u[8]; } o;
  o.u[0] = f2bf(lo.x); o.u[1] = f2bf(lo.y); o.u[2] = f2bf(lo.z); o.u[3] = f2bf(lo.w);
  o.u[4] = f2bf(hi.x); o.u[5] = f2bf(hi.y); o.u[6] = f2bf(hi.z); o.u[7] = f2bf(hi.w);
  return o.v;
}

__device__ __forceinline__ f32x4 mfma16(bf16x8 a, bf16x8 b, f32x4 c) {
  return __builtin_amdgcn_mfma_f32_16x16x32_bf16(a, b, c, 0, 0, 0);
}

// ---------------- P2: weights -> B^T bf16; bias gather ----------------
__global__ void k_prep(const float* __restrict__ qkv_w, const float* __restrict__ proj_w,
                       const float* __restrict__ rpb, const int* __restrict__ rel,
                       u16* __restrict__ wqkvt, u16* __restrict__ wprojt,
                       float* __restrict__ biasar) {
  int tid = blockIdx.x * blockDim.x + threadIdx.x;
  int stride = gridDim.x * blockDim.x;
  for (int i = tid; i < 768 * 256; i += stride) {
    int n = i >> 8, k = i & 255;
    wqkvt[i] = f2bf(qkv_w[(size_t)k * 768 + n]);
  }
  for (int i = tid; i < 256 * 256; i += stride) {
    int n = i >> 8, k = i & 255;
    wprojt[i] = f2bf(proj_w[(size_t)k * 256 + n]);
  }
  for (int i = tid; i < NW * NW; i += stride) {
    int idv = rel[i];
#pragma unroll
    for (int hh = 0; hh < 8; ++hh) biasar[hh * (NW * NW) + i] = rpb[idv * 8 + hh];
  }
}

// ---------------- Persistent-M GEMM: out[M][N] = A[M][256] * Bt[N][256]^T + bias --
// K=256 is tiny => B slice lives in REGISTERS (32 bf16x8/wave, loaded once/block);
// A M-tile (128x256 bf16 = 64KB) lives fully in LDS, double-buffered (128KB).
// Each block streams TPB=9 consecutive M-tiles: prefetch t+1 (global->reg->LDS in
// two halves around compute) while computing t. ONE barrier per tile (vs 8 before).
// Stores issued after the barrier so they overlap the next tile's compute.
template <int NT, bool AF32, bool OUTF32>
__global__ __launch_bounds__(512, 2) void k_gemm_persist(const void* __restrict__ Av,
                                                         const u16* __restrict__ Bt,
                                                         const float* __restrict__ bias,
                                                         void* __restrict__ outv) {
  constexpr int N = NT * 128;
  constexpr int TPB = 9;            // 2304 M-tiles = 256 groups * 9
  __shared__ __align__(16) u16 As[2][128 * 256];

  int tid = threadIdx.x;
  int wave = tid >> 6, lane = tid & 63;
  int ln = lane & 15, quad = lane >> 4;
  int wm = wave >> 1, wn = wave & 1;   // 8 waves: 4 M-rows x 2 N-cols, wave tile 32x64

  // XCD swizzle (bijective): the NT column-blocks of one M-group share an XCD.
  int bid = blockIdx.x;
  int xcd = bid & 7, slot = bid >> 3;
  int g = xcd * 32 + slot / NT;     // 256 groups / 8 XCDs = 32
  int nt = slot % NT;
  int n0 = nt * 128;
  int m0base = g * (TPB * 128);

  // B fragments in registers, reused across all TPB M-tiles (128 VGPR).
  bf16x8 bfr[8][4];
#pragma unroll
  for (int ks = 0; ks < 8; ++ks)
#pragma unroll
    for (int j = 0; j < 4; ++j)
      bfr[ks][j] = *(const bf16x8*)&Bt[(size_t)(n0 + wn * 64 + j * 16 + ln) * 256 + ks * 32 + quad * 8];

  // Prologue: stage A tile 0 into As[0]. Per thread: 8 pairs of 16B bf16 chunks.
  // LDS layout [r][256] bf16, 16B-chunk index XOR-swizzled by (r&7) -> conflict-free.
#pragma unroll
  for (int i = 0; i < 8; ++i) {
    int p = i * 512 + tid;
    int r = p >> 5, pc = p & 31;
    bf16x8 v;
    if constexpr (AF32) {
      const float* ptr = &((const float*)Av)[(size_t)(m0base + r) * 256 + pc * 8];
      v = pack8(*(const f32x4*)ptr, *(const f32x4*)(ptr + 4));
    } else {
      v = *(const bf16x8*)&((const u16*)Av)[(size_t)(m0base + r) * 256 + pc * 8];
    }
    *(bf16x8*)&As[0][r * 256 + ((pc ^ (r & 7)) << 3)] = v;
  }
  __syncthreads();

  f32x4 zero4 = {0.f, 0.f, 0.f, 0.f};

  for (int t = 0; t < TPB; ++t) {
    int cur = t & 1, nxt = cur ^ 1;
    int m0 = m0base + t * 128;
    bool hn = (t + 1 < TPB);
    const u16* curs = &As[cur][0];
    u16* nxts = &As[nxt][0];

    f32x4 acc[2][4];
#pragma unroll
    for (int i = 0; i < 2; ++i)
#pragma unroll
      for (int j = 0; j < 4; ++j) acc[i][j] = zero4;

    f32x4 lo[4], hi[4];
    bf16x8 pv[4];

    // ---- issue half-0 loads of A(t+1) (rows 0..63)
    if (hn) {
#pragma unroll
      for (int i = 0; i < 4; ++i) {
        int p = i * 512 + tid;
        int r = p >> 5, pc = p & 31;
        if constexpr (AF32) {
          const float* ptr = &((const float*)Av)[(size_t)(m0 + 128 + r) * 256 + pc * 8];
          lo[i] = *(const f32x4*)ptr; hi[i] = *(const f32x4*)(ptr + 4);
        } else {
          pv[i] = *(const bf16x8*)&((const u16*)Av)[(size_t)(m0 + 128 + r) * 256 + pc * 8];
        }
      }
    }
    // ---- compute ks 0..3
#pragma unroll
    for (int ks = 0; ks < 4; ++ks) {
      bf16x8 af[2];
#pragma unroll
      for (int i = 0; i < 2; ++i) {
        int r = wm * 32 + i * 16 + ln;
        af[i] = *(const bf16x8*)&curs[r * 256 + (((ks * 4 + quad) ^ (r & 7)) << 3)];
      }
#pragma unroll
      for (int i = 0; i < 2; ++i)
#pragma unroll
        for (int j = 0; j < 4; ++j) acc[i][j] = mfma16(af[i], bfr[ks][j], acc[i][j]);
    }
    // ---- write half-0 into As[nxt] (other buffer: safe mid-tile)
    if (hn) {
#pragma unroll
      for (int i = 0; i < 4; ++i) {
        int p = i * 512 + tid;
        int r = p >> 5, pc = p & 31;
        bf16x8 v;
        if constexpr (AF32) v = pack8(lo[i], hi[i]); else v = pv[i];
        *(bf16x8*)&nxts[r * 256 + ((pc ^ (r & 7)) << 3)] = v;
      }
    }
    // ---- issue half-1 loads of A(t+1) (rows 64..127)
    if (hn) {
#pragma unroll
      for (int i = 0; i < 4; ++i) {
        int p = (4 + i) * 512 + tid;
        int r = p >> 5, pc = p & 31;
        if constexpr (AF32) {
          const float* ptr = &((const float*)Av)[(size_t)(m0 + 128 + r) * 256 + pc * 8];
          lo[i] = *(const f32x4*)ptr; hi[i] = *(const f32x4*)(ptr + 4);
        } else {
          pv[i] = *(const bf16x8*)&((const u16*)Av)[(size_t)(m0 + 128 + r) * 256 + pc * 8];
        }
      }
    }
    // ---- compute ks 4..7
#pragma unroll
    for (int ks = 4; ks < 8; ++ks) {
      bf16x8 af[2];
#pragma unroll
      for (int i = 0; i < 2; ++i) {
        int r = wm * 32 + i * 16 + ln;
        af[i] = *(const bf16x8*)&curs[r * 256 + (((ks * 4 + quad) ^ (r & 7)) << 3)];
      }
#pragma unroll
      for (int i = 0; i < 2; ++i)
#pragma unroll
        for (int j = 0; j < 4; ++j) acc[i][j] = mfma16(af[i], bfr[ks][j], acc[i][j]);
    }
    // ---- write half-1
    if (hn) {
#pragma unroll
      for (int i = 0; i < 4; ++i) {
        int p = (4 + i) * 512 + tid;
        int r = p >> 5, pc = p & 31;
        bf16x8 v;
        if constexpr (AF32) v = pack8(lo[i], hi[i]); else v = pv[i];
        *(bf16x8*)&nxts[r * 256 + ((pc ^ (r & 7)) << 3)] = v;
      }
    }
    if (hn) __syncthreads();   // uniform; As[nxt] ready, As[cur] free for t+2 writes

    // ---- epilogue tile t (after barrier: overlaps next tile's compute)
#pragma unroll
    for (int j = 0; j < 4; ++j) {
      int col = n0 + wn * 64 + j * 16 + ln;
      float bv = bias[col];
#pragma unroll
      for (int i = 0; i < 2; ++i) {
        int rbase = m0 + wm * 32 + i * 16 + quad * 4;
        f32x4 a = acc[i][j];
        if constexpr (OUTF32) {
          float* out = (float*)outv;
#pragma unroll
          for (int r = 0; r < 4; ++r) out[(size_t)(rbase + r) * N + col] = a[r] + bv;
        } else {
          u16* out = (u16*)outv;
#pragma unroll
          for (int r = 0; r < 4; ++r) out[(size_t)(rbase + r) * N + col] = f2bf(a[r] + bv);
        }
      }
    }
  }
}

// ---------------- K2: per-(window,head) attention (unchanged from R1) ----------
__global__ __launch_bounds__(192, 3) void k_attn(const u16* __restrict__ qkv,
                                                 const float* __restrict__ bias_arr,
                                                 u16* __restrict__ attn_out) {
  __shared__ __align__(16) u16 SqSk[144 * 40 * 2];
  __shared__ __align__(16) u16 Sv[32 * 160];   // v^T [d][m], m padded 144..159 = 0
  u16* Sq = SqSk;
  u16* Sk = SqSk + 144 * 40;
  u16* Sp = SqSk;                              // alias: live only after Sq/Sk dead

  int bid = blockIdx.x;
  int xcd = bid & 7, idx = bid >> 3;
  int w = xcd * 256 + (idx >> 3);
  int h = idx & 7;

  int tid = threadIdx.x;
  const u16* base = qkv + (size_t)w * (NW * 768);
  int qo = h * 32, ko = 256 + h * 32, vo = 512 + h * 32;

#pragma unroll
  for (int it = 0; it < 3; ++it) {
    int s = tid + it * 192;
    int r = s >> 2, c = (s & 3) << 3;
    *(bf16x8*)&Sq[r * 40 + c] = *(const bf16x8*)&base[(size_t)r * 768 + qo + c];
    *(bf16x8*)&Sk[r * 40 + c] = *(const bf16x8*)&base[(size_t)r * 768 + ko + c];
    bf16x8 vv = *(const bf16x8*)&base[(size_t)r * 768 + vo + c];
#pragma unroll
    for (int j = 0; j < 8; ++j) Sv[(c + j) * 160 + r] = ((u16*)&vv)[j];
  }
  for (int s = tid; s < 32 * 16; s += 192) {
    int d = s >> 4, m = 144 + (s & 15);
    Sv[d * 160 + m] = 0;
  }
  __syncthreads();

  int wv = tid >> 6;
  int lane = tid & 63, ln = lane & 15, quad = lane >> 4;

  f32x4 zero4 = {0.f, 0.f, 0.f, 0.f};
  f32x4 accs[3][9];
#pragma unroll
  for (int i = 0; i < 3; ++i)
#pragma unroll
    for (int j = 0; j < 9; ++j) accs[i][j] = zero4;

  bf16x8 aq[3];
#pragma unroll
  for (int mt = 0; mt < 3; ++mt) {
    int row = (wv * 3 + mt) * 16 + ln;
    aq[mt] = *(const bf16x8*)&Sq[row * 40 + quad * 8];
  }
#pragma unroll
  for (int j = 0; j < 9; ++j) {
    bf16x8 bk = *(const bf16x8*)&Sk[(j * 16 + ln) * 40 + quad * 8];
#pragma unroll
    for (int mt = 0; mt < 3; ++mt) accs[mt][j] = mfma16(aq[mt], bk, accs[mt][j]);
  }

  u16x4 pb[3][9];
  const float* bh = bias_arr + h * (NW * NW);
#pragma unroll
  for (int mt = 0; mt < 3; ++mt) {
#pragma unroll
    for (int r = 0; r < 4; ++r) {
      int n = (wv * 3 + mt) * 16 + quad * 4 + r;
      float sv[9];
      float mx = -3.0e38f;
#pragma unroll
      for (int j = 0; j < 9; ++j) {
        sv[j] = accs[mt][j][r] * SCALE + bh[n * 144 + j * 16 + ln];
        mx = fmaxf(mx, sv[j]);
      }
#pragma unroll
      for (int off = 1; off < 16; off <<= 1) mx = fmaxf(mx, __shfl_xor(mx, off));
      float sum = 0.f;
#pragma unroll
      for (int j = 0; j < 9; ++j) { sv[j] = __expf(sv[j] - mx); sum += sv[j]; }
#pragma unroll
      for (int off = 1; off < 16; off <<= 1) sum += __shfl_xor(sum, off);
      float inv = 1.f / sum;
#pragma unroll
      for (int j = 0; j < 9; ++j) pb[mt][j][r] = f2bf(sv[j] * inv);
    }
  }

  f32x4 acco[3][2];
#pragma unroll
  for (int i = 0; i < 3; ++i) { acco[i][0] = zero4; acco[i][1] = zero4; }

#pragma unroll
  for (int cc = 0; cc < 3; ++cc) {
    __syncthreads();
    int njj = (cc == 2) ? 2 : 4;
#pragma unroll
    for (int mt = 0; mt < 3; ++mt)
#pragma unroll
      for (int r = 0; r < 4; ++r) {
        int n = (wv * 3 + mt) * 16 + quad * 4 + r;
#pragma unroll
        for (int jj = 0; jj < 4; ++jj) {
          if (jj >= njj) break;
          int jg = cc * 4 + jj;
          u16 val;
          if (jg < 9) val = pb[mt][jg][r]; else val = (u16)0;
          Sp[n * 72 + jj * 16 + ln] = val;
        }
      }
    __syncthreads();
    int nks = (cc == 2) ? 1 : 2;
#pragma unroll
    for (int ks = 0; ks < 2; ++ks) {
      if (ks >= nks) break;
      int kg = cc * 64 + ks * 32;
      bf16x8 bv0 = *(const bf16x8*)&Sv[ln * 160 + kg + quad * 8];
      bf16x8 bv1 = *(const bf16x8*)&Sv[(16 + ln) * 160 + kg + quad * 8];
#pragma unroll
      for (int mt = 0; mt < 3; ++mt) {
        int row = (wv * 3 + mt) * 16 + ln;
        bf16x8 ap = *(const bf16x8*)&Sp[row * 72 + ks * 32 + quad * 8];
        acco[mt][0] = mfma16(ap, bv0, acco[mt][0]);
        acco[mt][1] = mfma16(ap, bv1, acco[mt][1]);
      }
    }
  }

  u16* op = attn_out + (size_t)w * (NW * 256) + h * 32;
#pragma unroll
  for (int mt = 0; mt < 3; ++mt)
#pragma unroll
    for (int d2 = 0; d2 < 2; ++d2) {
      f32x4 a = acco[mt][d2];
      int col = d2 * 16 + ln;
#pragma unroll
      for (int r = 0; r < 4; ++r) {
        int n = (wv * 3 + mt) * 16 + quad * 4 + r;
        op[(size_t)n * 256 + col] = f2bf(a[r]);
      }
    }
}

// ---------------- launcher ----------------
extern "C" void kernel_launch(void* const* d_in, const int* in_sizes, int n_in,
                              void* d_out, int out_size, void* d_ws, size_t ws_size,
                              hipStream_t stream) {
  const float* x      = (const float*)d_in[0];
  const float* qkv_w  = (const float*)d_in[1];
  const float* qkv_b  = (const float*)d_in[2];
  const float* proj_w = (const float*)d_in[3];
  const float* proj_b = (const float*)d_in[4];
  const float* rpb    = (const float*)d_in[5];
  const int*   rel    = (const int*)d_in[6];
  float* out = (float*)d_out;

  u16* qkv    = (u16*)d_ws;
  u16* attno  = qkv + (size_t)MTOT * 768;
  u16* wqkvt  = attno + (size_t)MTOT * 256;
  u16* wprojt = wqkvt + 768 * 256;
  float* biasar = (float*)(wprojt + 256 * 256);

  k_prep<<<256, 256, 0, stream>>>(qkv_w, proj_w, rpb, rel, wqkvt, wprojt, biasar);
  k_gemm_persist<6, true,  false><<<1536, 512, 0, stream>>>(x, wqkvt, qkv_b, (void*)qkv);
  k_attn<<<16384, 192, 0, stream>>>(qkv, biasar, attno);
  k_gemm_persist<2, false, true><<<512, 512, 0, stream>>>(attno, wprojt, proj_b, (void*)out);
}